// Round 2
// baseline (1030.357 us; speedup 1.0000x reference)
//
#include <hip/hip_runtime.h>
#include <stdint.h>

#define DIM 192
#define HEADS 6
#define HW 16384
#define CO 576
#define K9 1728

typedef __attribute__((ext_vector_type(8))) short bf16x8;
typedef __attribute__((ext_vector_type(4))) float f32x4;

__device__ __forceinline__ unsigned short f2bf(float f) {
  union { float f; unsigned u; } v; v.f = f;
  unsigned r = v.u + 0x7FFFu + ((v.u >> 16) & 1u);
  return (unsigned short)(r >> 16);
}

// ---- reorder qkv_w OIHW fp32 -> wbf[o][rs*192+ci] bf16 ----
__global__ __launch_bounds__(256) void k_reorder_w(const float* __restrict__ w,
                                                   unsigned short* __restrict__ wbf) {
  int g = blockIdx.x * 256 + threadIdx.x;
  if (g >= CO * K9) return;
  int o = g / K9, rem = g % K9;
  int rs = rem / DIM, ci = rem % DIM;
  wbf[g] = f2bf(w[(o * DIM + ci) * 9 + rs]);
}

// ---- x NCHW fp32 -> NHWC bf16 ----
__global__ __launch_bounds__(256) void k_nhwc(const float* __restrict__ x,
                                              unsigned short* __restrict__ xbf) {
  int g = blockIdx.x * 256 + threadIdx.x;   // 8*128*128*24 threads
  int xcol = g & 127;
  int t2 = g >> 7;
  int c24 = t2 % 24;
  int t3 = t2 / 24;
  int y = t3 & 127;
  int n = t3 >> 7;
  union { unsigned short u[8]; uint4 v; } pk;
#pragma unroll
  for (int i = 0; i < 8; ++i)
    pk.u[i] = f2bf(x[((size_t)(n * DIM + c24 * 8 + i) * 128 + y) * 128 + xcol]);
  *(uint4*)&xbf[(size_t)((n * 128 + y) * 128 + xcol) * DIM + c24 * 8] = pk.v;
}

// ---- implicit-GEMM 3x3 conv: qkv[n][c][p] bf16, fp32 acc ----
// tile: 64 outch x 256 pixels (2 image rows), BK=64, 27 chunks (9 shifts x 3 ci-blocks)
__global__ __launch_bounds__(256) void k_conv(const unsigned short* __restrict__ xbf,
                                              const unsigned short* __restrict__ wbf,
                                              unsigned short* __restrict__ qkv) {
  __shared__ char smem[2 * 40960];   // per buf: A 64x64x2B=8KB, B 256x64x2B=32KB
  const int tid = threadIdx.x;
  const int lane = tid & 63;
  const int wv = tid >> 6;
  const int lane15 = lane & 15;
  const int lgrp = lane >> 4;
  const int c0 = blockIdx.x * 64;
  const int by = blockIdx.y;
  const int n = blockIdx.z;
  const int y0 = by * 2;

  f32x4 acc[4][4] = {};
  uint4 sreg[10];

  auto stage_load = [&](int t) {
    int rs = t / 3;
    int ci0 = (t % 3) * 64;
    int r = rs / 3, s = rs % 3;
#pragma unroll
    for (int rr = 0; rr < 2; ++rr) {           // A tile
      int off = tid * 16 + rr * 4096;
      int row = off >> 7;
      int cb = off & 127;
      int scb = cb ^ ((row & 7) << 4);
      const char* gp = (const char*)wbf + (size_t)((c0 + row) * K9 + rs * DIM + ci0) * 2 + scb;
      sreg[rr] = *(const uint4*)gp;
    }
    int yb = y0 + r - 1;
#pragma unroll
    for (int rr = 0; rr < 8; ++rr) {           // B tile
      int off = tid * 16 + rr * 4096;
      int prow = off >> 7;
      int cb = off & 127;
      int scb = cb ^ ((prow & 7) << 4);
      int yy = yb + (prow >> 7);
      int xx = (prow & 127) + s - 1;
      if (yy < 0 || yy > 127 || xx < 0 || xx > 127) {
        sreg[2 + rr] = make_uint4(0u, 0u, 0u, 0u);
      } else {
        const char* gp = (const char*)xbf +
            (size_t)(((n * 128 + yy) * 128 + xx) * DIM + ci0) * 2 + scb;
        sreg[2 + rr] = *(const uint4*)gp;
      }
    }
  };

  auto ds_write_tile = [&](int buf) {
    char* Ab = smem + buf * 40960;
#pragma unroll
    for (int rr = 0; rr < 2; ++rr) *(uint4*)(Ab + tid * 16 + rr * 4096) = sreg[rr];
    char* Bb = Ab + 8192;
#pragma unroll
    for (int rr = 0; rr < 8; ++rr) *(uint4*)(Bb + tid * 16 + rr * 4096) = sreg[2 + rr];
  };

  auto compute = [&](int buf) {
    char* Ab = smem + buf * 40960;
    char* Bb = Ab + 8192;
#pragma unroll
    for (int k32 = 0; k32 < 2; ++k32) {
      int kb = k32 * 64 + lgrp * 16;
      bf16x8 a[4], b[4];
#pragma unroll
      for (int m = 0; m < 4; ++m) {
        int row = m * 16 + lane15;
        a[m] = *(bf16x8*)(Ab + row * 128 + (kb ^ ((row & 7) << 4)));
      }
#pragma unroll
      for (int nb = 0; nb < 4; ++nb) {
        int p = wv * 64 + nb * 16 + lane15;
        b[nb] = *(bf16x8*)(Bb + p * 128 + (kb ^ ((p & 7) << 4)));
      }
#pragma unroll
      for (int m = 0; m < 4; ++m)
#pragma unroll
        for (int nb = 0; nb < 4; ++nb)
          acc[m][nb] = __builtin_amdgcn_mfma_f32_16x16x32_bf16(a[m], b[nb], acc[m][nb], 0, 0, 0);
    }
  };

  stage_load(0);
  ds_write_tile(0);
  __syncthreads();
  int cur = 0;
  for (int t = 0; t < 27; ++t) {
    if (t + 1 < 27) stage_load(t + 1);   // issue-early: overlap with compute
    compute(cur);
    __syncthreads();
    if (t + 1 < 27) ds_write_tile(cur ^ 1);
    __syncthreads();
    cur ^= 1;
  }

#pragma unroll
  for (int m = 0; m < 4; ++m)
#pragma unroll
    for (int nb = 0; nb < 4; ++nb)
#pragma unroll
      for (int j = 0; j < 4; ++j) {
        int c = c0 + m * 16 + lgrp * 4 + j;
        int pix = wv * 64 + nb * 16 + lane15;
        qkv[(size_t)(n * CO + c) * HW + by * 256 + pix] = f2bf(acc[m][nb][j]);
      }
}

// ---- Gram: G[n,h][64][64] = [q;k][q;k]^T over 16384 pixels (diag = norms^2) ----
__global__ __launch_bounds__(256) void k_gram(const unsigned short* __restrict__ qkv,
                                              float* __restrict__ G) {
  const int pc = blockIdx.x, h = blockIdx.y, n = blockIdx.z;
  const int tid = threadIdx.x, lane = tid & 63, wv = tid >> 6;
  const int lane15 = lane & 15, lgrp = lane >> 4;
  const unsigned short* base[4];
#pragma unroll
  for (int mi = 0; mi < 4; ++mi) {
    int ch = mi * 16 + lane15;
    int cg = (ch < 32) ? (h * 32 + ch) : (DIM + h * 32 + ch - 32);
    base[mi] = qkv + (size_t)(n * CO + cg) * HW;
  }
  f32x4 acc[4][4] = {};
  int pbase = pc * 2048 + wv * 512;
  for (int st = 0; st < 16; ++st) {
    int p = pbase + st * 32 + lgrp * 8;
    bf16x8 f[4];
#pragma unroll
    for (int mi = 0; mi < 4; ++mi) f[mi] = *(const bf16x8*)(base[mi] + p);
#pragma unroll
    for (int mi = 0; mi < 4; ++mi)
#pragma unroll
      for (int ni = 0; ni < 4; ++ni)
        acc[mi][ni] = __builtin_amdgcn_mfma_f32_16x16x32_bf16(f[mi], f[ni], acc[mi][ni], 0, 0, 0);
  }
  float* Gm = G + (size_t)(n * HEADS + h) * 4096;
#pragma unroll
  for (int mi = 0; mi < 4; ++mi)
#pragma unroll
    for (int ni = 0; ni < 4; ++ni)
#pragma unroll
      for (int j = 0; j < 4; ++j) {
        int row = mi * 16 + lgrp * 4 + j;
        int col = ni * 16 + lane15;
        atomicAdd(&Gm[row * 64 + col], acc[mi][ni][j]);
      }
}

// ---- v transpose: vt[n][p][dg] = qkv[n][384+dg][p] ----
__global__ __launch_bounds__(256) void k_vt(const unsigned short* __restrict__ qkv,
                                            unsigned short* __restrict__ vt) {
  int g = blockIdx.x * 256 + threadIdx.x;   // 8*24*16384
  int p = g & 16383;
  int t2 = g >> 14;
  int c24 = t2 % 24;
  int n = t2 / 24;
  union { unsigned short u[8]; uint4 v; } pk;
#pragma unroll
  for (int i = 0; i < 8; ++i)
    pk.u[i] = qkv[(size_t)(n * CO + 2 * DIM + c24 * 8 + i) * HW + p];
  *(uint4*)&vt[(size_t)(n * HW + p) * DIM + c24 * 8] = pk.v;
}

// ---- softmax + fold projection: M[n] = proj_w @ blockdiag(attn) , bf16 ----
__global__ __launch_bounds__(256) void k_attnm(const float* __restrict__ G,
                                               const float* __restrict__ temp,
                                               const float* __restrict__ projw,
                                               unsigned short* __restrict__ Mbf) {
  __shared__ float attn_s[HEADS][32][32];
  int n = blockIdx.x, tid = threadIdx.x;
  if (tid < 192) {
    int h = tid >> 5, c = tid & 31;
    const float* Gm = G + (size_t)(n * HEADS + h) * 4096;
    float nq = fmaxf(sqrtf(Gm[c * 64 + c]), 1e-12f);
    float tp = temp[h];
    float l[32];
    float mx = -1e30f;
#pragma unroll
    for (int d = 0; d < 32; ++d) {
      float nk = fmaxf(sqrtf(Gm[(32 + d) * 64 + 32 + d]), 1e-12f);
      l[d] = Gm[c * 64 + 32 + d] / (nq * nk) * tp;
      mx = fmaxf(mx, l[d]);
    }
    float sum = 0.f;
#pragma unroll
    for (int d = 0; d < 32; ++d) { l[d] = expf(l[d] - mx); sum += l[d]; }
    float inv = 1.f / sum;
#pragma unroll
    for (int d = 0; d < 32; ++d) attn_s[h][c][d] = l[d] * inv;
  }
  __syncthreads();
  for (int idx = tid; idx < DIM * DIM; idx += 256) {
    int o = idx / DIM, dg = idx % DIM;
    int h = dg >> 5, d = dg & 31;
    float s = 0.f;
#pragma unroll
    for (int c = 0; c < 32; ++c)
      s += projw[o * DIM + h * 32 + c] * attn_s[h][c][d];
    Mbf[(size_t)(n * DIM + o) * DIM + dg] = f2bf(s);
  }
}

// ---- final GEMM: out[n][o][p] = sum_dg M[n][o][dg]*vt[n][p][dg] + bias[o] ----
__global__ __launch_bounds__(256) void k_out(const unsigned short* __restrict__ Mbf,
                                             const unsigned short* __restrict__ vt,
                                             const float* __restrict__ bias,
                                             float* __restrict__ out) {
  __shared__ char smem[2 * 40960];
  const int tid = threadIdx.x;
  const int lane = tid & 63;
  const int wv = tid >> 6;
  const int lane15 = lane & 15;
  const int lgrp = lane >> 4;
  const int c0 = blockIdx.x * 64;
  const int p0 = blockIdx.y * 256;
  const int n = blockIdx.z;

  f32x4 acc[4][4] = {};
  uint4 sreg[10];

  auto stage_load = [&](int t) {
#pragma unroll
    for (int rr = 0; rr < 2; ++rr) {
      int off = tid * 16 + rr * 4096;
      int row = off >> 7;
      int cb = off & 127;
      int scb = cb ^ ((row & 7) << 4);
      const char* gp = (const char*)Mbf + (size_t)(n * DIM + c0 + row) * 384 + t * 128 + scb;
      sreg[rr] = *(const uint4*)gp;
    }
#pragma unroll
    for (int rr = 0; rr < 8; ++rr) {
      int off = tid * 16 + rr * 4096;
      int prow = off >> 7;
      int cb = off & 127;
      int scb = cb ^ ((prow & 7) << 4);
      const char* gp = (const char*)vt + (size_t)(n * HW + p0 + prow) * 384 + t * 128 + scb;
      sreg[2 + rr] = *(const uint4*)gp;
    }
  };

  auto ds_write_tile = [&](int buf) {
    char* Ab = smem + buf * 40960;
#pragma unroll
    for (int rr = 0; rr < 2; ++rr) *(uint4*)(Ab + tid * 16 + rr * 4096) = sreg[rr];
    char* Bb = Ab + 8192;
#pragma unroll
    for (int rr = 0; rr < 8; ++rr) *(uint4*)(Bb + tid * 16 + rr * 4096) = sreg[2 + rr];
  };

  auto compute = [&](int buf) {
    char* Ab = smem + buf * 40960;
    char* Bb = Ab + 8192;
#pragma unroll
    for (int k32 = 0; k32 < 2; ++k32) {
      int kb = k32 * 64 + lgrp * 16;
      bf16x8 a[4], b[4];
#pragma unroll
      for (int m = 0; m < 4; ++m) {
        int row = m * 16 + lane15;
        a[m] = *(bf16x8*)(Ab + row * 128 + (kb ^ ((row & 7) << 4)));
      }
#pragma unroll
      for (int nb = 0; nb < 4; ++nb) {
        int p = wv * 64 + nb * 16 + lane15;
        b[nb] = *(bf16x8*)(Bb + p * 128 + (kb ^ ((p & 7) << 4)));
      }
#pragma unroll
      for (int m = 0; m < 4; ++m)
#pragma unroll
        for (int nb = 0; nb < 4; ++nb)
          acc[m][nb] = __builtin_amdgcn_mfma_f32_16x16x32_bf16(a[m], b[nb], acc[m][nb], 0, 0, 0);
    }
  };

  stage_load(0);
  ds_write_tile(0);
  __syncthreads();
  int cur = 0;
  for (int t = 0; t < 3; ++t) {
    if (t + 1 < 3) stage_load(t + 1);
    compute(cur);
    __syncthreads();
    if (t + 1 < 3) ds_write_tile(cur ^ 1);
    __syncthreads();
    cur ^= 1;
  }

#pragma unroll
  for (int m = 0; m < 4; ++m)
#pragma unroll
    for (int nb = 0; nb < 4; ++nb)
#pragma unroll
      for (int j = 0; j < 4; ++j) {
        int c = c0 + m * 16 + lgrp * 4 + j;
        int pix = wv * 64 + nb * 16 + lane15;
        out[(size_t)(n * DIM + c) * HW + p0 + pix] = acc[m][nb][j] + bias[c];
      }
}

extern "C" void kernel_launch(void* const* d_in, const int* in_sizes, int n_in,
                              void* d_out, int out_size, void* d_ws, size_t ws_size,
                              hipStream_t stream) {
  const float* x      = (const float*)d_in[0];
  const float* qkv_w  = (const float*)d_in[1];
  const float* proj_w = (const float*)d_in[2];
  const float* proj_b = (const float*)d_in[3];
  const float* temp   = (const float*)d_in[4];
  float* out = (float*)d_out;

  char* ws = (char*)d_ws;
  float* G            = (float*)ws;                                 // 786432 B
  unsigned short* wbf = (unsigned short*)(ws + 786688);             // 1990656 B
  unsigned short* qkv = (unsigned short*)(ws + 2777344);            // 150994944 B
  unsigned short* Mbf = (unsigned short*)(ws + 153772288);          // 589824 B
  unsigned short* xbf = (unsigned short*)(ws + 154362112);          // 50331648 B
  unsigned short* vt  = xbf;  // alias: xbf dead after conv

  (void)hipMemsetAsync(G, 0, 48 * 64 * 64 * 4, stream);
  k_reorder_w<<<(CO * K9 + 255) / 256, 256, 0, stream>>>(qkv_w, wbf);
  k_nhwc<<<12288, 256, 0, stream>>>(x, xbf);
  k_conv<<<dim3(9, 64, 8), 256, 0, stream>>>(xbf, wbf, qkv);
  k_gram<<<dim3(8, HEADS, 8), 256, 0, stream>>>(qkv, G);
  k_vt<<<12288, 256, 0, stream>>>(qkv, vt);        // after conv: overwrites xbf
  k_attnm<<<8, 256, 0, stream>>>(G, temp, proj_w, Mbf);
  k_out<<<dim3(3, 64, 8), 256, 0, stream>>>(Mbf, vt, proj_b, out);
}

// Round 3
// 757.744 us; speedup vs baseline: 1.3598x; 1.3598x over previous
//
#include <hip/hip_runtime.h>
#include <stdint.h>

#define DIM 192
#define HEADS 6
#define HW 16384
#define CO 576
#define K9 1728
#define CQK 384   // q,k channels stored in qkv buffer

typedef __attribute__((ext_vector_type(8))) short bf16x8;
typedef __attribute__((ext_vector_type(4))) float f32x4;

__device__ __forceinline__ unsigned short f2bf(float f) {
  union { float f; unsigned u; } v; v.f = f;
  unsigned r = v.u + 0x7FFFu + ((v.u >> 16) & 1u);
  return (unsigned short)(r >> 16);
}

__device__ __forceinline__ void gll16(const void* g, void* l) {
  __builtin_amdgcn_global_load_lds(
      (const __attribute__((address_space(1))) unsigned int*)g,
      (__attribute__((address_space(3))) unsigned int*)l, 16, 0, 0);
}

// ---- reorder qkv_w OIHW fp32 -> wbf[o][rs*192+ci] bf16 ----
__global__ __launch_bounds__(256) void k_reorder_w(const float* __restrict__ w,
                                                   unsigned short* __restrict__ wbf) {
  int g = blockIdx.x * 256 + threadIdx.x;
  if (g >= CO * K9) return;
  int o = g / K9, rem = g % K9;
  int rs = rem / DIM, ci = rem % DIM;
  wbf[g] = f2bf(w[(o * DIM + ci) * 9 + rs]);
}

// ---- x NCHW fp32 -> NHWC bf16 ----
__global__ __launch_bounds__(256) void k_nhwc(const float* __restrict__ x,
                                              unsigned short* __restrict__ xbf) {
  int g = blockIdx.x * 256 + threadIdx.x;   // 8*128*128*24 threads
  int xcol = g & 127;
  int t2 = g >> 7;
  int c24 = t2 % 24;
  int t3 = t2 / 24;
  int y = t3 & 127;
  int n = t3 >> 7;
  union { unsigned short u[8]; uint4 v; } pk;
#pragma unroll
  for (int i = 0; i < 8; ++i)
    pk.u[i] = f2bf(x[((size_t)(n * DIM + c24 * 8 + i) * 128 + y) * 128 + xcol]);
  *(uint4*)&xbf[(size_t)((n * 128 + y) * 128 + xcol) * DIM + c24 * 8] = pk.v;
}

// ---- implicit-GEMM 3x3 conv, global_load_lds + XCD-local grid ----
// grid 4608 1D; XCD x owns image n=x; 9 c-blocks of a pixel group adjacent.
// q,k blocks (cblk<6) -> qkv[n][c][p]; v blocks -> vt[n][p][dg] (transposed).
__global__ __launch_bounds__(256) void k_conv(const unsigned short* __restrict__ xbf,
                                              const unsigned short* __restrict__ wbf,
                                              const char* __restrict__ zeros,
                                              unsigned short* __restrict__ qkv,
                                              unsigned short* __restrict__ vt) {
  __shared__ char smem[2 * 40960];   // per buf: A 64x64x2B=8KB, B 256x64x2B=32KB
  const int tid = threadIdx.x;
  const int lane = tid & 63;
  const int wv = tid >> 6;
  const int lane15 = lane & 15;
  const int lgrp = lane >> 4;

  int p = blockIdx.x;
  int xcd = p & 7;
  int slot = p >> 3;                 // 0..575
  int work = xcd * 576 + slot;
  int cblk = work % 9;
  int g = work / 9;                  // 0..511
  const int by = g & 63;
  const int n = g >> 6;
  const int c0 = cblk * 64;
  const int y0 = by * 2;

  f32x4 acc[4][4] = {};

  auto stage = [&](int t, int buf) {
    int rs = t / 3;
    int ci0 = (t % 3) * 64;
    int r = rs / 3, s = rs % 3;
    char* base = smem + buf * 40960;
#pragma unroll
    for (int rr = 0; rr < 2; ++rr) {           // A tile (weights)
      int off = tid * 16 + rr * 4096;
      int row = off >> 7;
      int scb = (off & 127) ^ ((row & 7) << 4);
      const char* gp = (const char*)wbf + (size_t)((c0 + row) * K9 + rs * DIM + ci0) * 2 + scb;
      gll16(gp, base + rr * 4096 + wv * 1024);
    }
    int yb = y0 + r - 1;
#pragma unroll
    for (int rr = 0; rr < 8; ++rr) {           // B tile (pixels)
      int off = tid * 16 + rr * 4096;
      int prow = off >> 7;
      int scb = (off & 127) ^ ((prow & 7) << 4);
      int yy = yb + (prow >> 7);
      int xx = (prow & 127) + s - 1;
      const char* gp;
      if (yy < 0 || yy > 127 || xx < 0 || xx > 127)
        gp = zeros + scb;                       // zero-filled guard region
      else
        gp = (const char*)xbf + (size_t)(((n * 128 + yy) * 128 + xx) * DIM + ci0) * 2 + scb;
      gll16(gp, base + 8192 + rr * 4096 + wv * 1024);
    }
  };

  auto compute = [&](int buf) {
    char* Ab = smem + buf * 40960;
    char* Bb = Ab + 8192;
#pragma unroll
    for (int k32 = 0; k32 < 2; ++k32) {
      int kb = k32 * 64 + lgrp * 16;
      bf16x8 a[4], b[4];
#pragma unroll
      for (int m = 0; m < 4; ++m) {
        int row = m * 16 + lane15;
        a[m] = *(bf16x8*)(Ab + row * 128 + (kb ^ ((row & 7) << 4)));
      }
#pragma unroll
      for (int nb = 0; nb < 4; ++nb) {
        int pp = wv * 64 + nb * 16 + lane15;
        b[nb] = *(bf16x8*)(Bb + pp * 128 + (kb ^ ((pp & 7) << 4)));
      }
#pragma unroll
      for (int m = 0; m < 4; ++m)
#pragma unroll
        for (int nb = 0; nb < 4; ++nb)
          acc[m][nb] = __builtin_amdgcn_mfma_f32_16x16x32_bf16(a[m], b[nb], acc[m][nb], 0, 0, 0);
    }
  };

  stage(0, 0);
  __syncthreads();
  int cur = 0;
  for (int t = 0; t < 27; ++t) {
    if (t < 26) stage(t + 1, cur ^ 1);   // loads overlap compute; barrier drains them
    compute(cur);
    __syncthreads();
    cur ^= 1;
  }

  // ---- epilogue: stage tile in LDS (buf0), store coalesced 16B/lane ----
  char* st = smem;
  if (cblk < 6) {
    // row-major [c][512B], 16B-chunk XOR swizzle
#pragma unroll
    for (int m = 0; m < 4; ++m)
#pragma unroll
      for (int nb = 0; nb < 4; ++nb) {
        int pix = wv * 64 + nb * 16 + lane15;
#pragma unroll
        for (int j = 0; j < 4; ++j) {
          int c = m * 16 + lgrp * 4 + j;
          *(unsigned short*)(st + c * 512 + ((pix * 2) ^ ((c & 7) << 4))) = f2bf(acc[m][nb][j]);
        }
      }
    __syncthreads();
    int c = tid >> 2, q4 = tid & 3;
    char* dst = (char*)qkv + ((size_t)(n * CQK + c0 + c) * HW + by * 256 + q4 * 64) * 2;
#pragma unroll
    for (int i = 0; i < 8; ++i) {
      uint4 vv = *(uint4*)(st + c * 512 + ((q4 * 128 + i * 16) ^ ((c & 7) << 4)));
      *(uint4*)(dst + i * 16) = vv;
    }
  } else {
    // transposed [pix][128B] -> vt[n][p][dg]
    int dg0 = c0 - 384;
#pragma unroll
    for (int m = 0; m < 4; ++m)
#pragma unroll
      for (int nb = 0; nb < 4; ++nb) {
        int pix = wv * 64 + nb * 16 + lane15;
        int cl = m * 16 + lgrp * 4;
        union { unsigned short u[4]; uint2 v; } pk;
#pragma unroll
        for (int j = 0; j < 4; ++j) pk.u[j] = f2bf(acc[m][nb][j]);
        *(uint2*)(st + pix * 128 + ((cl * 2) ^ ((pix & 7) << 4))) = pk.v;
      }
    __syncthreads();
    char* dst = (char*)vt + ((size_t)(n * HW + by * 256 + tid) * DIM + dg0) * 2;
#pragma unroll
    for (int i = 0; i < 8; ++i) {
      uint4 vv = *(uint4*)(st + tid * 128 + ((i * 16) ^ ((tid & 7) << 4)));
      *(uint4*)(dst + i * 16) = vv;
    }
  }
}

// ---- Gram: G[n,h][64][64] = [q;k][q;k]^T over 16384 pixels (diag = norms^2) ----
__global__ __launch_bounds__(256) void k_gram(const unsigned short* __restrict__ qkv,
                                              float* __restrict__ G) {
  const int pc = blockIdx.x, h = blockIdx.y, n = blockIdx.z;
  const int tid = threadIdx.x, lane = tid & 63, wv = tid >> 6;
  const int lane15 = lane & 15, lgrp = lane >> 4;
  const unsigned short* base[4];
#pragma unroll
  for (int mi = 0; mi < 4; ++mi) {
    int ch = mi * 16 + lane15;
    int cg = (ch < 32) ? (h * 32 + ch) : (DIM + h * 32 + ch - 32);
    base[mi] = qkv + (size_t)(n * CQK + cg) * HW;
  }
  f32x4 acc[4][4] = {};
  int pbase = pc * 2048 + wv * 512;
  for (int st = 0; st < 16; ++st) {
    int p = pbase + st * 32 + lgrp * 8;
    bf16x8 f[4];
#pragma unroll
    for (int mi = 0; mi < 4; ++mi) f[mi] = *(const bf16x8*)(base[mi] + p);
#pragma unroll
    for (int mi = 0; mi < 4; ++mi)
#pragma unroll
      for (int ni = 0; ni < 4; ++ni)
        acc[mi][ni] = __builtin_amdgcn_mfma_f32_16x16x32_bf16(f[mi], f[ni], acc[mi][ni], 0, 0, 0);
  }
  float* Gm = G + (size_t)(n * HEADS + h) * 4096;
#pragma unroll
  for (int mi = 0; mi < 4; ++mi)
#pragma unroll
    for (int ni = 0; ni < 4; ++ni)
#pragma unroll
      for (int j = 0; j < 4; ++j) {
        int row = mi * 16 + lgrp * 4 + j;
        int col = ni * 16 + lane15;
        atomicAdd(&Gm[row * 64 + col], acc[mi][ni][j]);
      }
}

// ---- softmax + fold projection: M[n] = proj_w @ blockdiag(attn) , bf16 ----
__global__ __launch_bounds__(256) void k_attnm(const float* __restrict__ G,
                                               const float* __restrict__ temp,
                                               const float* __restrict__ projw,
                                               unsigned short* __restrict__ Mbf) {
  __shared__ float attn_s[HEADS][32][32];
  int n = blockIdx.x, tid = threadIdx.x;
  if (tid < 192) {
    int h = tid >> 5, c = tid & 31;
    const float* Gm = G + (size_t)(n * HEADS + h) * 4096;
    float nq = fmaxf(sqrtf(Gm[c * 64 + c]), 1e-12f);
    float tp = temp[h];
    float l[32];
    float mx = -1e30f;
#pragma unroll
    for (int d = 0; d < 32; ++d) {
      float nk = fmaxf(sqrtf(Gm[(32 + d) * 64 + 32 + d]), 1e-12f);
      l[d] = Gm[c * 64 + 32 + d] / (nq * nk) * tp;
      mx = fmaxf(mx, l[d]);
    }
    float sum = 0.f;
#pragma unroll
    for (int d = 0; d < 32; ++d) { l[d] = expf(l[d] - mx); sum += l[d]; }
    float inv = 1.f / sum;
#pragma unroll
    for (int d = 0; d < 32; ++d) attn_s[h][c][d] = l[d] * inv;
  }
  __syncthreads();
  for (int idx = tid; idx < DIM * DIM; idx += 256) {
    int o = idx / DIM, dg = idx % DIM;
    int h = dg >> 5, d = dg & 31;
    float s = 0.f;
#pragma unroll
    for (int c = 0; c < 32; ++c)
      s += projw[o * DIM + h * 32 + c] * attn_s[h][c][d];
    Mbf[(size_t)(n * DIM + o) * DIM + dg] = f2bf(s);
  }
}

// ---- final GEMM: out[n][o][p] = sum_dg M[n][o][dg]*vt[n][p][dg] + bias[o] ----
__global__ __launch_bounds__(256) void k_out(const unsigned short* __restrict__ Mbf,
                                             const unsigned short* __restrict__ vt,
                                             const float* __restrict__ bias,
                                             float* __restrict__ out) {
  __shared__ char smem[2 * 40960];
  const int tid = threadIdx.x;
  const int lane = tid & 63;
  const int wv = tid >> 6;
  const int lane15 = lane & 15;
  const int lgrp = lane >> 4;
  const int c0 = blockIdx.x * 64;
  const int p0 = blockIdx.y * 256;
  const int n = blockIdx.z;

  f32x4 acc[4][4] = {};

  auto stage = [&](int t, int buf) {
    char* base = smem + buf * 40960;
#pragma unroll
    for (int rr = 0; rr < 2; ++rr) {
      int off = tid * 16 + rr * 4096;
      int row = off >> 7;
      int scb = (off & 127) ^ ((row & 7) << 4);
      const char* gp = (const char*)Mbf + (size_t)(n * DIM + c0 + row) * 384 + t * 128 + scb;
      gll16(gp, base + rr * 4096 + wv * 1024);
    }
#pragma unroll
    for (int rr = 0; rr < 8; ++rr) {
      int off = tid * 16 + rr * 4096;
      int prow = off >> 7;
      int scb = (off & 127) ^ ((prow & 7) << 4);
      const char* gp = (const char*)vt + (size_t)(n * HW + p0 + prow) * 384 + t * 128 + scb;
      gll16(gp, base + 8192 + rr * 4096 + wv * 1024);
    }
  };

  auto compute = [&](int buf) {
    char* Ab = smem + buf * 40960;
    char* Bb = Ab + 8192;
#pragma unroll
    for (int k32 = 0; k32 < 2; ++k32) {
      int kb = k32 * 64 + lgrp * 16;
      bf16x8 a[4], b[4];
#pragma unroll
      for (int m = 0; m < 4; ++m) {
        int row = m * 16 + lane15;
        a[m] = *(bf16x8*)(Ab + row * 128 + (kb ^ ((row & 7) << 4)));
      }
#pragma unroll
      for (int nb = 0; nb < 4; ++nb) {
        int pp = wv * 64 + nb * 16 + lane15;
        b[nb] = *(bf16x8*)(Bb + pp * 128 + (kb ^ ((pp & 7) << 4)));
      }
#pragma unroll
      for (int m = 0; m < 4; ++m)
#pragma unroll
        for (int nb = 0; nb < 4; ++nb)
          acc[m][nb] = __builtin_amdgcn_mfma_f32_16x16x32_bf16(a[m], b[nb], acc[m][nb], 0, 0, 0);
    }
  };

  stage(0, 0);
  __syncthreads();
  int cur = 0;
  for (int t = 0; t < 3; ++t) {
    if (t < 2) stage(t + 1, cur ^ 1);
    compute(cur);
    __syncthreads();
    cur ^= 1;
  }

#pragma unroll
  for (int m = 0; m < 4; ++m)
#pragma unroll
    for (int nb = 0; nb < 4; ++nb)
#pragma unroll
      for (int j = 0; j < 4; ++j) {
        int c = c0 + m * 16 + lgrp * 4 + j;
        int pix = wv * 64 + nb * 16 + lane15;
        out[(size_t)(n * DIM + c) * HW + p0 + pix] = acc[m][nb][j] + bias[c];
      }
}

extern "C" void kernel_launch(void* const* d_in, const int* in_sizes, int n_in,
                              void* d_out, int out_size, void* d_ws, size_t ws_size,
                              hipStream_t stream) {
  const float* x      = (const float*)d_in[0];
  const float* qkv_w  = (const float*)d_in[1];
  const float* proj_w = (const float*)d_in[2];
  const float* proj_b = (const float*)d_in[3];
  const float* temp   = (const float*)d_in[4];
  float* out = (float*)d_out;

  char* ws = (char*)d_ws;
  float* G            = (float*)ws;                        // 786432 B
  const char* zeros   = ws + 786432;                       // 256 B guard (zeroed)
  unsigned short* wbf = (unsigned short*)(ws + 786688);    // 1990656 B
  unsigned short* qkv = (unsigned short*)(ws + 2777344);   // q,k: 100663296 B
  unsigned short* Mbf = (unsigned short*)(ws + 103440640); // 589824 B
  unsigned short* xbf = (unsigned short*)(ws + 104030464); // 50331648 B
  unsigned short* vt  = (unsigned short*)(ws + 154362112); // 50331648 B

  (void)hipMemsetAsync(ws, 0, 786688, stream);             // G + zeros guard
  k_reorder_w<<<(CO * K9 + 255) / 256, 256, 0, stream>>>(qkv_w, wbf);
  k_nhwc<<<12288, 256, 0, stream>>>(x, xbf);
  k_conv<<<4608, 256, 0, stream>>>(xbf, wbf, zeros, qkv, vt);
  k_gram<<<dim3(8, HEADS, 8), 256, 0, stream>>>(qkv, G);
  k_attnm<<<8, 256, 0, stream>>>(G, temp, proj_w, Mbf);
  k_out<<<dim3(3, 64, 8), 256, 0, stream>>>(Mbf, vt, proj_b, out);
}

// Round 4
// 644.557 us; speedup vs baseline: 1.5986x; 1.1756x over previous
//
#include <hip/hip_runtime.h>
#include <stdint.h>

#define DIM 192
#define HEADS 6
#define HW 16384
#define CO 576
#define K9 1728
#define CQK 384   // q,k channels stored in qkv buffer

typedef __attribute__((ext_vector_type(8))) short bf16x8;
typedef __attribute__((ext_vector_type(4))) float f32x4;

__device__ __forceinline__ unsigned short f2bf(float f) {
  union { float f; unsigned u; } v; v.f = f;
  unsigned r = v.u + 0x7FFFu + ((v.u >> 16) & 1u);
  return (unsigned short)(r >> 16);
}

__device__ __forceinline__ void gll16(const void* g, void* l) {
  __builtin_amdgcn_global_load_lds(
      (const __attribute__((address_space(1))) unsigned int*)g,
      (__attribute__((address_space(3))) unsigned int*)l, 16, 0, 0);
}

// ---- reorder qkv_w OIHW fp32 -> wbf[o][rs*192+ci] bf16 ----
__global__ __launch_bounds__(256) void k_reorder_w(const float* __restrict__ w,
                                                   unsigned short* __restrict__ wbf) {
  int g = blockIdx.x * 256 + threadIdx.x;
  if (g >= CO * K9) return;
  int o = g / K9, rem = g % K9;
  int rs = rem / DIM, ci = rem % DIM;
  wbf[g] = f2bf(w[(o * DIM + ci) * 9 + rs]);
}

// ---- x NCHW fp32 -> NHWC bf16 ----
__global__ __launch_bounds__(256) void k_nhwc(const float* __restrict__ x,
                                              unsigned short* __restrict__ xbf) {
  int g = blockIdx.x * 256 + threadIdx.x;   // 8*128*128*24 threads
  int xcol = g & 127;
  int t2 = g >> 7;
  int c24 = t2 % 24;
  int t3 = t2 / 24;
  int y = t3 & 127;
  int n = t3 >> 7;
  union { unsigned short u[8]; uint4 v; } pk;
#pragma unroll
  for (int i = 0; i < 8; ++i)
    pk.u[i] = f2bf(x[((size_t)(n * DIM + c24 * 8 + i) * 128 + y) * 128 + xcol]);
  *(uint4*)&xbf[(size_t)((n * 128 + y) * 128 + xcol) * DIM + c24 * 8] = pk.v;
}

// ---- implicit-GEMM 3x3 conv, global_load_lds + XCD-local grid ----
// SINGLE-buffered LDS (40KB) + occupancy: 4 blocks/CU; overlap comes from
// other resident blocks (m97 regime), not a manual double buffer.
__global__ __launch_bounds__(256, 4) void k_conv(const unsigned short* __restrict__ xbf,
                                                 const unsigned short* __restrict__ wbf,
                                                 const char* __restrict__ zeros,
                                                 unsigned short* __restrict__ qkv,
                                                 unsigned short* __restrict__ vt) {
  __shared__ char smem[40960];   // A 64x64x2B=8KB, B 256x64x2B=32KB
  const int tid = threadIdx.x;
  const int lane = tid & 63;
  const int wv = tid >> 6;
  const int lane15 = lane & 15;
  const int lgrp = lane >> 4;

  int p = blockIdx.x;
  int xcd = p & 7;
  int slot = p >> 3;                 // 0..575
  int work = xcd * 576 + slot;
  int cblk = work % 9;
  int g = work / 9;                  // 0..511
  const int by = g & 63;
  const int n = g >> 6;
  const int c0 = cblk * 64;
  const int y0 = by * 2;

  f32x4 acc[4][4] = {};

  auto stage = [&](int t) {
    int rs = t / 3;
    int ci0 = (t % 3) * 64;
    int r = rs / 3, s = rs % 3;
#pragma unroll
    for (int rr = 0; rr < 2; ++rr) {           // A tile (weights)
      int off = tid * 16 + rr * 4096;
      int row = off >> 7;
      int scb = (off & 127) ^ ((row & 7) << 4);
      const char* gp = (const char*)wbf + (size_t)((c0 + row) * K9 + rs * DIM + ci0) * 2 + scb;
      gll16(gp, smem + rr * 4096 + wv * 1024);
    }
    int yb = y0 + r - 1;
#pragma unroll
    for (int rr = 0; rr < 8; ++rr) {           // B tile (pixels)
      int off = tid * 16 + rr * 4096;
      int prow = off >> 7;
      int scb = (off & 127) ^ ((prow & 7) << 4);
      int yy = yb + (prow >> 7);
      int xx = (prow & 127) + s - 1;
      const char* gp;
      if (yy < 0 || yy > 127 || xx < 0 || xx > 127)
        gp = zeros + scb;                       // zero-filled guard region
      else
        gp = (const char*)xbf + (size_t)(((n * 128 + yy) * 128 + xx) * DIM + ci0) * 2 + scb;
      gll16(gp, smem + 8192 + rr * 4096 + wv * 1024);
    }
  };

  auto compute = [&]() {
    char* Ab = smem;
    char* Bb = smem + 8192;
#pragma unroll
    for (int k32 = 0; k32 < 2; ++k32) {
      int kb = k32 * 64 + lgrp * 16;
      bf16x8 a[4], b[4];
#pragma unroll
      for (int m = 0; m < 4; ++m) {
        int row = m * 16 + lane15;
        a[m] = *(bf16x8*)(Ab + row * 128 + (kb ^ ((row & 7) << 4)));
      }
#pragma unroll
      for (int nb = 0; nb < 4; ++nb) {
        int pp = wv * 64 + nb * 16 + lane15;
        b[nb] = *(bf16x8*)(Bb + pp * 128 + (kb ^ ((pp & 7) << 4)));
      }
#pragma unroll
      for (int m = 0; m < 4; ++m)
#pragma unroll
        for (int nb = 0; nb < 4; ++nb)
          acc[m][nb] = __builtin_amdgcn_mfma_f32_16x16x32_bf16(a[m], b[nb], acc[m][nb], 0, 0, 0);
    }
  };

  for (int t = 0; t < 27; ++t) {
    stage(t);
    __syncthreads();     // drains global_load_lds; other resident blocks overlap
    compute();
    __syncthreads();     // protect LDS before next stage
  }

  // ---- epilogue: stage tile in LDS, store coalesced 16B/lane ----
  char* st = smem;
  if (cblk < 6) {
    // row-major [c][512B], 16B-chunk XOR swizzle
#pragma unroll
    for (int m = 0; m < 4; ++m)
#pragma unroll
      for (int nb = 0; nb < 4; ++nb) {
        int pix = wv * 64 + nb * 16 + lane15;
#pragma unroll
        for (int j = 0; j < 4; ++j) {
          int c = m * 16 + lgrp * 4 + j;
          *(unsigned short*)(st + c * 512 + ((pix * 2) ^ ((c & 7) << 4))) = f2bf(acc[m][nb][j]);
        }
      }
    __syncthreads();
    int c = tid >> 2, q4 = tid & 3;
    char* dst = (char*)qkv + ((size_t)(n * CQK + c0 + c) * HW + by * 256 + q4 * 64) * 2;
#pragma unroll
    for (int i = 0; i < 8; ++i) {
      uint4 vv = *(uint4*)(st + c * 512 + ((q4 * 128 + i * 16) ^ ((c & 7) << 4)));
      *(uint4*)(dst + i * 16) = vv;
    }
  } else {
    // transposed [pix][128B] -> vt[n][p][dg]
    int dg0 = c0 - 384;
#pragma unroll
    for (int m = 0; m < 4; ++m)
#pragma unroll
      for (int nb = 0; nb < 4; ++nb) {
        int pix = wv * 64 + nb * 16 + lane15;
        int cl = m * 16 + lgrp * 4;
        union { unsigned short u[4]; uint2 v; } pk;
#pragma unroll
        for (int j = 0; j < 4; ++j) pk.u[j] = f2bf(acc[m][nb][j]);
        *(uint2*)(st + pix * 128 + ((cl * 2) ^ ((pix & 7) << 4))) = pk.v;
      }
    __syncthreads();
    char* dst = (char*)vt + ((size_t)(n * HW + by * 256 + tid) * DIM + dg0) * 2;
#pragma unroll
    for (int i = 0; i < 8; ++i) {
      uint4 vv = *(uint4*)(st + tid * 128 + ((i * 16) ^ ((tid & 7) << 4)));
      *(uint4*)(dst + i * 16) = vv;
    }
  }
}

// ---- Gram: G[n,h][64][64] = [q;k][q;k]^T over 16384 pixels (diag = norms^2) ----
__global__ __launch_bounds__(256) void k_gram(const unsigned short* __restrict__ qkv,
                                              float* __restrict__ G) {
  const int pc = blockIdx.x, h = blockIdx.y, n = blockIdx.z;
  const int tid = threadIdx.x, lane = tid & 63, wv = tid >> 6;
  const int lane15 = lane & 15, lgrp = lane >> 4;
  const unsigned short* base[4];
#pragma unroll
  for (int mi = 0; mi < 4; ++mi) {
    int ch = mi * 16 + lane15;
    int cg = (ch < 32) ? (h * 32 + ch) : (DIM + h * 32 + ch - 32);
    base[mi] = qkv + (size_t)(n * CQK + cg) * HW;
  }
  f32x4 acc[4][4] = {};
  int pbase = pc * 2048 + wv * 512;
  for (int st = 0; st < 16; ++st) {
    int p = pbase + st * 32 + lgrp * 8;
    bf16x8 f[4];
#pragma unroll
    for (int mi = 0; mi < 4; ++mi) f[mi] = *(const bf16x8*)(base[mi] + p);
#pragma unroll
    for (int mi = 0; mi < 4; ++mi)
#pragma unroll
      for (int ni = 0; ni < 4; ++ni)
        acc[mi][ni] = __builtin_amdgcn_mfma_f32_16x16x32_bf16(f[mi], f[ni], acc[mi][ni], 0, 0, 0);
  }
  float* Gm = G + (size_t)(n * HEADS + h) * 4096;
#pragma unroll
  for (int mi = 0; mi < 4; ++mi)
#pragma unroll
    for (int ni = 0; ni < 4; ++ni)
#pragma unroll
      for (int j = 0; j < 4; ++j) {
        int row = mi * 16 + lgrp * 4 + j;
        int col = ni * 16 + lane15;
        atomicAdd(&Gm[row * 64 + col], acc[mi][ni][j]);
      }
}

// ---- softmax + fold projection: M[n] = proj_w @ blockdiag(attn) , bf16 ----
__global__ __launch_bounds__(256) void k_attnm(const float* __restrict__ G,
                                               const float* __restrict__ temp,
                                               const float* __restrict__ projw,
                                               unsigned short* __restrict__ Mbf) {
  __shared__ float attn_s[HEADS][32][32];
  int n = blockIdx.x, tid = threadIdx.x;
  if (tid < 192) {
    int h = tid >> 5, c = tid & 31;
    const float* Gm = G + (size_t)(n * HEADS + h) * 4096;
    float nq = fmaxf(sqrtf(Gm[c * 64 + c]), 1e-12f);
    float tp = temp[h];
    float l[32];
    float mx = -1e30f;
#pragma unroll
    for (int d = 0; d < 32; ++d) {
      float nk = fmaxf(sqrtf(Gm[(32 + d) * 64 + 32 + d]), 1e-12f);
      l[d] = Gm[c * 64 + 32 + d] / (nq * nk) * tp;
      mx = fmaxf(mx, l[d]);
    }
    float sum = 0.f;
#pragma unroll
    for (int d = 0; d < 32; ++d) { l[d] = expf(l[d] - mx); sum += l[d]; }
    float inv = 1.f / sum;
#pragma unroll
    for (int d = 0; d < 32; ++d) attn_s[h][c][d] = l[d] * inv;
  }
  __syncthreads();
  for (int idx = tid; idx < DIM * DIM; idx += 256) {
    int o = idx / DIM, dg = idx % DIM;
    int h = dg >> 5, d = dg & 31;
    float s = 0.f;
#pragma unroll
    for (int c = 0; c < 32; ++c)
      s += projw[o * DIM + h * 32 + c] * attn_s[h][c][d];
    Mbf[(size_t)(n * DIM + o) * DIM + dg] = f2bf(s);
  }
}

// ---- final GEMM: out[n][o][p] = sum_dg M[n][o][dg]*vt[n][p][dg] + bias[o] ----
__global__ __launch_bounds__(256, 4) void k_out(const unsigned short* __restrict__ Mbf,
                                                const unsigned short* __restrict__ vt,
                                                const float* __restrict__ bias,
                                                float* __restrict__ out) {
  __shared__ char smem[40960];
  const int tid = threadIdx.x;
  const int lane = tid & 63;
  const int wv = tid >> 6;
  const int lane15 = lane & 15;
  const int lgrp = lane >> 4;
  const int c0 = blockIdx.x * 64;
  const int p0 = blockIdx.y * 256;
  const int n = blockIdx.z;

  f32x4 acc[4][4] = {};

  auto stage = [&](int t) {
#pragma unroll
    for (int rr = 0; rr < 2; ++rr) {
      int off = tid * 16 + rr * 4096;
      int row = off >> 7;
      int scb = (off & 127) ^ ((row & 7) << 4);
      const char* gp = (const char*)Mbf + (size_t)(n * DIM + c0 + row) * 384 + t * 128 + scb;
      gll16(gp, smem + rr * 4096 + wv * 1024);
    }
#pragma unroll
    for (int rr = 0; rr < 8; ++rr) {
      int off = tid * 16 + rr * 4096;
      int prow = off >> 7;
      int scb = (off & 127) ^ ((prow & 7) << 4);
      const char* gp = (const char*)vt + (size_t)(n * HW + p0 + prow) * 384 + t * 128 + scb;
      gll16(gp, smem + 8192 + rr * 4096 + wv * 1024);
    }
  };

  auto compute = [&]() {
    char* Ab = smem;
    char* Bb = smem + 8192;
#pragma unroll
    for (int k32 = 0; k32 < 2; ++k32) {
      int kb = k32 * 64 + lgrp * 16;
      bf16x8 a[4], b[4];
#pragma unroll
      for (int m = 0; m < 4; ++m) {
        int row = m * 16 + lane15;
        a[m] = *(bf16x8*)(Ab + row * 128 + (kb ^ ((row & 7) << 4)));
      }
#pragma unroll
      for (int nb = 0; nb < 4; ++nb) {
        int pp = wv * 64 + nb * 16 + lane15;
        b[nb] = *(bf16x8*)(Bb + pp * 128 + (kb ^ ((pp & 7) << 4)));
      }
#pragma unroll
      for (int m = 0; m < 4; ++m)
#pragma unroll
        for (int nb = 0; nb < 4; ++nb)
          acc[m][nb] = __builtin_amdgcn_mfma_f32_16x16x32_bf16(a[m], b[nb], acc[m][nb], 0, 0, 0);
    }
  };

  for (int t = 0; t < 3; ++t) {
    stage(t);
    __syncthreads();
    compute();
    __syncthreads();
  }

#pragma unroll
  for (int m = 0; m < 4; ++m)
#pragma unroll
    for (int nb = 0; nb < 4; ++nb)
#pragma unroll
      for (int j = 0; j < 4; ++j) {
        int c = c0 + m * 16 + lgrp * 4 + j;
        int pix = wv * 64 + nb * 16 + lane15;
        out[(size_t)(n * DIM + c) * HW + p0 + pix] = acc[m][nb][j] + bias[c];
      }
}

extern "C" void kernel_launch(void* const* d_in, const int* in_sizes, int n_in,
                              void* d_out, int out_size, void* d_ws, size_t ws_size,
                              hipStream_t stream) {
  const float* x      = (const float*)d_in[0];
  const float* qkv_w  = (const float*)d_in[1];
  const float* proj_w = (const float*)d_in[2];
  const float* proj_b = (const float*)d_in[3];
  const float* temp   = (const float*)d_in[4];
  float* out = (float*)d_out;

  char* ws = (char*)d_ws;
  float* G            = (float*)ws;                        // 786432 B
  const char* zeros   = ws + 786432;                       // 256 B guard (zeroed)
  unsigned short* wbf = (unsigned short*)(ws + 786688);    // 1990656 B
  unsigned short* qkv = (unsigned short*)(ws + 2777344);   // q,k: 100663296 B
  unsigned short* Mbf = (unsigned short*)(ws + 103440640); // 589824 B
  unsigned short* xbf = (unsigned short*)(ws + 104030464); // 50331648 B
  unsigned short* vt  = (unsigned short*)(ws + 154362112); // 50331648 B

  (void)hipMemsetAsync(ws, 0, 786688, stream);             // G + zeros guard
  k_reorder_w<<<(CO * K9 + 255) / 256, 256, 0, stream>>>(qkv_w, wbf);
  k_nhwc<<<12288, 256, 0, stream>>>(x, xbf);
  k_conv<<<4608, 256, 0, stream>>>(xbf, wbf, zeros, qkv, vt);
  k_gram<<<dim3(8, HEADS, 8), 256, 0, stream>>>(qkv, G);
  k_attnm<<<8, 256, 0, stream>>>(G, temp, proj_w, Mbf);
  k_out<<<dim3(3, 64, 8), 256, 0, stream>>>(Mbf, vt, proj_b, out);
}